// Round 11
// baseline (376.463 us; speedup 1.0000x reference)
//
#include <hip/hip_runtime.h>

namespace {

typedef __attribute__((ext_vector_type(8))) short short8;   // MFMA A/B frag (8 bf16)
typedef __attribute__((ext_vector_type(4))) float floatx4;  // MFMA C/D frag

constexpr int T    = 512;
constexpr int H    = 64;
constexpr int TPB  = 256;   // 4 waves/block; grid 512 -> 2 blocks/CU = 2 waves/SIMD,
                            // barrier-DECOUPLED (R10 showed paired waves lockstep)
constexpr int MB   = 4;     // 4 batches per block
constexpr int HBU  = 144;   // h row stride (ushorts): [0,64)=hi, [72,136)=lo
constexpr int LOFF = 72;
constexpr int XSTR = 516;   // xs row stride (floats)
constexpr int FSTR = 68;    // hf32 row stride (floats, head only)

constexpr int SWZ_XOR4 = 0x101F;  // ds_swizzle BitMode: xor lane^4, and=0x1F

__device__ __forceinline__ ushort f2bf(float x) {  // fp32 -> bf16 RN-even (finite)
  unsigned u = __float_as_uint(x);
  unsigned r = u + 0x7fffu + ((u >> 16) & 1u);
  return (ushort)(r >> 16);
}
__device__ __forceinline__ float bf2f(ushort h) {
  return __uint_as_float(((unsigned)h) << 16);
}
__device__ __forceinline__ float fsig(float x) {
  return __builtin_amdgcn_rcpf(1.0f + __expf(-x));
}
__device__ __forceinline__ float ftanh(float x) {
  return fmaf(-2.0f, __builtin_amdgcn_rcpf(1.0f + __expf(2.0f * x)), 1.0f);
}
__device__ __forceinline__ float swzx4(float v) {   // value from lane^4 (in-wave)
  return __int_as_float(__builtin_amdgcn_ds_swizzle(__float_as_int(v), SWZ_XOR4));
}

// R11: quadrant-packed split GEMM, 4 batches/block, 2 blocks/CU.
//   B cols: col n -> batch n&3, type (n>>2)&1 (0=hi,1=lo); quadrants 2,3 read
//   the same LDS rows as 0,1 (lane-broadcast duplication, free).
//   Per gate: d1 = Whi x B (K=64, 2 MFMA), d2 = Wlo x B (2 MFMA);
//   s[r] = d1[r]+d2[r]; lane owns row q = n>>2:
//     gate[q] = s[q] + swzx4(s[q^1]) + bias + x*Wih   (4-term fp32 split).
//   (lane^4 flips hi/lo within the same batch; partner sends my row's
//    other-type part — same own/snd structure verified in R9.)
//   One c-state per lane: unit u = 16*wj + 4*kg + q, batch n&3.
// Layouts (verified R5/R9): A[m=lane&15][k=8*(lane>>4)+j]; B[k][n=lane&15];
// D col=lane&15, row=4*(lane>>4)+reg.
__global__ __launch_bounds__(TPB, 2)
void lstm_mfma(const float* __restrict__ xg,
               const float* __restrict__ W_ih,
               const float* __restrict__ W_hh,
               const float* __restrict__ b_ih,
               const float* __restrict__ b_hh,
               const float* __restrict__ fc1_w,
               const float* __restrict__ fc1_b,
               const float* __restrict__ fc2_w,
               const float* __restrict__ fc2_b,
               float* __restrict__ out)
{
  __shared__ __align__(16) ushort hA[MB * HBU];   // h double-buffer (hi | lo regions)
  __shared__ __align__(16) ushort hB[MB * HBU];
  __shared__ __align__(16) float  xs[MB * XSTR];
  __shared__ __align__(16) float  hf[MB * FSTR];  // final h fp32 (head; written once)
  __shared__ float zs[MB][16];

  const int tid  = threadIdx.x;
  const int b0   = blockIdx.x * MB;
  const int lane = tid & 63;
  const int wj   = tid >> 6;       // wave 0..3 -> unit tile
  const int n    = lane & 15;      // MFMA col
  const int kg   = lane >> 4;      // k-group (A/B), row-quad (D)
  const int bat  = n & 3;          // batch
  const int q    = n >> 2;         // quadrant: owned row = 4kg+q; type = q&1
  const bool c1  = (q & 1) != 0;
  const bool c2  = (q & 2) != 0;

  // ---- stage x (coalesced float4) ----
  for (int i = tid; i < MB * T / 4; i += TPB) {
    const int xb = i >> 7, tq = i & 127;
    float4 v = ((const float4*)(xg + (size_t)(b0 + xb) * T))[tq];
    *(float4*)&xs[xb * XSTR + tq * 4] = v;
  }
  // ---- zero h buffers (h0 = 0; pads stay 0) ----
  for (int i = tid; i < MB * HBU; i += TPB) { hA[i] = 0; hB[i] = 0; }

  // ---- static W fragments (A-operands; layout verified R5/R9) ----
  short8 whi0[4], whi1[4], wlo0[4], wlo1[4];
#pragma unroll
  for (int g = 0; g < 4; ++g) {
    const int arow = 64 * g + 16 * wj + n;          // this lane's A-frag row
    const float* wr = W_hh + arow * H + 8 * kg;     // k slice [8kg,8kg+8) and +32
    const float4 p0 = *(const float4*)(wr + 0);
    const float4 p1 = *(const float4*)(wr + 4);
    const float4 p2 = *(const float4*)(wr + 32);
    const float4 p3 = *(const float4*)(wr + 36);
    const float v0[8] = {p0.x, p0.y, p0.z, p0.w, p1.x, p1.y, p1.z, p1.w};
    const float v1[8] = {p2.x, p2.y, p2.z, p2.w, p3.x, p3.y, p3.z, p3.w};
#pragma unroll
    for (int j = 0; j < 8; ++j) {
      const ushort h0 = f2bf(v0[j]);
      whi0[g][j] = (short)h0;
      wlo0[g][j] = (short)f2bf(v0[j] - bf2f(h0));   // exact remainder, then RN
      const ushort h1 = f2bf(v1[j]);
      whi1[g][j] = (short)h1;
      wlo1[g][j] = (short)f2bf(v1[j] - bf2f(h1));
    }
  }
  // bias + W_ih for the single owned row per gate
  float bia[4], wih[4];
#pragma unroll
  for (int g = 0; g < 4; ++g) {
    const int drow = 64 * g + 16 * wj + 4 * kg + q;
    bia[g] = b_ih[drow] + b_hh[drow];
    wih[g] = W_ih[drow];
  }

  const int rdoff = bat * HBU + LOFF * (q & 1) + 8 * kg;  // B-frag read base
  const int u     = 16 * wj + 4 * kg + q;                 // owned unit
  const int hwoff = bat * HBU + u;                        // h hi write index
  const float* xq = &xs[bat * XSTR];
  float c = 0.0f, hk = 0.0f;

  __syncthreads();

#define STEP(HR, HW, TT)                                                       \
  {                                                                            \
    const ushort* hb = (HR) + rdoff;                                           \
    const short8 f0 = *(const short8*)(hb + 0);    /* k 0..31  (hi or lo) */   \
    const short8 f1 = *(const short8*)(hb + 32);   /* k 32..63 */              \
    const floatx4 zf = {0.f, 0.f, 0.f, 0.f};                                   \
    const float xt = xq[(TT)];                                                 \
    float p[4];                                                                \
    _Pragma("unroll") for (int g = 0; g < 4; ++g) {                            \
      floatx4 d1 = __builtin_amdgcn_mfma_f32_16x16x32_bf16(whi0[g], f0, zf, 0, 0, 0); \
      floatx4 d2 = __builtin_amdgcn_mfma_f32_16x16x32_bf16(wlo0[g], f0, zf, 0, 0, 0); \
      d1 = __builtin_amdgcn_mfma_f32_16x16x32_bf16(whi1[g], f1, d1, 0, 0, 0);  \
      d2 = __builtin_amdgcn_mfma_f32_16x16x32_bf16(wlo1[g], f1, d2, 0, 0, 0);  \
      const float s0 = d1[0] + d2[0];                                          \
      const float s1 = d1[1] + d2[1];                                          \
      const float s2 = d1[2] + d2[2];                                          \
      const float s3 = d1[3] + d2[3];                                          \
      const float own = c2 ? (c1 ? s3 : s2) : (c1 ? s1 : s0);                  \
      const float snd = c2 ? (c1 ? s2 : s3) : (c1 ? s0 : s1);                  \
      p[g] = own + swzx4(snd) + fmaf(xt, wih[g], bia[g]);                      \
    }                                                                          \
    const float ig = fsig(p[0]);                                               \
    const float fg = fsig(p[1]);                                               \
    const float gc = ftanh(p[2]);                                              \
    const float og = fsig(p[3]);                                               \
    c  = fmaf(fg, c, ig * gc);                                                 \
    hk = og * ftanh(c);                                                        \
    const ushort hib = f2bf(hk);                                               \
    ushort* hw = (HW) + hwoff;                                                 \
    hw[0]    = hib;                                                            \
    hw[LOFF] = f2bf(hk - bf2f(hib));                                           \
    __syncthreads();                                                           \
  }

  for (int t = 0; t < T; t += 2) {
    STEP(hA, hB, t);
    STEP(hB, hA, t + 1);
  }
#undef STEP

  // ---- final h (fp32, from registers) -> LDS once; then the head ----
  hf[bat * FSTR + u] = hk;
  __syncthreads();
  if (tid < MB * 16) {
    const int bq = tid >> 4, j2 = tid & 15;   // 4 batches x 16 hidden2
    float s = fc1_b[j2];
    const float* fw = fc1_w + j2 * H;
#pragma unroll
    for (int k = 0; k < H; ++k) s = fmaf(hf[bq * FSTR + k], fw[k], s);
    s = fmaxf(s, 0.0f);
    zs[bq][j2] = s * fc2_w[j2];
  }
  __syncthreads();
  if (tid < MB) {
    float s = fc2_b[0];
#pragma unroll
    for (int j = 0; j < 16; ++j) s += zs[tid][j];
    out[b0 + tid] = s;
  }
}

}  // namespace

extern "C" void kernel_launch(void* const* d_in, const int* in_sizes, int n_in,
                              void* d_out, int out_size, void* d_ws, size_t ws_size,
                              hipStream_t stream) {
  const float* xg    = (const float*)d_in[0];
  const float* W_ih  = (const float*)d_in[1];
  const float* W_hh  = (const float*)d_in[2];
  const float* b_ih  = (const float*)d_in[3];
  const float* b_hh  = (const float*)d_in[4];
  const float* fc1_w = (const float*)d_in[5];
  const float* fc1_b = (const float*)d_in[6];
  const float* fc2_w = (const float*)d_in[7];
  const float* fc2_b = (const float*)d_in[8];
  float* out = (float*)d_out;

  dim3 grid(2048 / MB);   // 512 blocks -> 2 per CU (barrier-decoupled waves/SIMD)
  dim3 block(TPB);
  hipLaunchKernelGGL(lstm_mfma, grid, block, 0, stream,
                     xg, W_ih, W_hh, b_ih, b_hh, fc1_w, fc1_b, fc2_w, fc2_b, out);
}

// Round 12
// 298.235 us; speedup vs baseline: 1.2623x; 1.2623x over previous
//
#include <hip/hip_runtime.h>

namespace {

typedef __attribute__((ext_vector_type(8))) short short8;   // MFMA A/B frag (8 bf16)
typedef __attribute__((ext_vector_type(4))) float floatx4;  // MFMA C/D frag

constexpr int T    = 512;
constexpr int H    = 64;
constexpr int TPB  = 512;   // 8 waves = 2/SIMD; grid 256 -> all CUs (R6+R9 lesson)
constexpr int MB   = 8;     // 8 batches per block
constexpr int HST  = 136;   // h row stride (ushorts): [0,64)=hi, [64,128)=lo, 8 pad
constexpr int XSTR = 516;   // xs row stride (floats)
constexpr int FSTR = 68;    // hf32 row stride (floats, head only)

constexpr int DPP_ROR8 = 0x128;  // row_ror:8 -> lane i reads lane i^8 (within row of 16)

__device__ __forceinline__ ushort f2bf(float x) {  // fp32 -> bf16 RN-even (finite)
  unsigned u = __float_as_uint(x);
  unsigned r = u + 0x7fffu + ((u >> 16) & 1u);
  return (ushort)(r >> 16);
}
__device__ __forceinline__ float bf2f(ushort h) {
  return __uint_as_float(((unsigned)h) << 16);
}
__device__ __forceinline__ float fsig(float x) {
  return __builtin_amdgcn_rcpf(1.0f + __expf(-x));
}
__device__ __forceinline__ float ftanh(float x) {
  return fmaf(-2.0f, __builtin_amdgcn_rcpf(1.0f + __expf(2.0f * x)), 1.0f);
}
__device__ __forceinline__ float swz8(float v) {   // value from lane^8 (row of 16)
  return __int_as_float(__builtin_amdgcn_update_dpp(
      0, __float_as_int(v), DPP_ROR8, 0xf, 0xf, true));
}

// R12: gate-interleaved A-row permutation.
//   A row m of tile r loads W_hh row 64*(m&3) + 4r + (m>>2)  (gate g=m&3,
//   local unit ul=m>>2). Then D reg j (row 4kg+j) = gate j of unit 4r+kg:
//   ALL FOUR GATES of one (unit,batch) land in one lane's D regs.
//   B cols (verified R9): 0-7 = h_hi(batch 0-7), 8-15 = h_lo(batch 0-7) -> no
//   MFMA waste. Per tile: d1 = Whi x B (2 MFMA, K=64), d2 = Wlo x B (2 MFMA);
//   s[j] = d1[j]+d2[j]; full 4-term preact p[j] = s[j] + swz8(s[j])
//   (symmetric hi/lo col merge, verified R9 exchange).
//   8 waves x 2 tiles; lane (n,kg) of wave wj owns c-state of
//   unit 4*(2wj + (n>>3)) + kg, batch n&7  -> 512 lanes = 512 c-states, 1 each.
//   One barrier/step (h is cross-wave); h double-buffered.
__global__ __launch_bounds__(TPB, 2)
void lstm_mfma(const float* __restrict__ xg,
               const float* __restrict__ W_ih,
               const float* __restrict__ W_hh,
               const float* __restrict__ b_ih,
               const float* __restrict__ b_hh,
               const float* __restrict__ fc1_w,
               const float* __restrict__ fc1_b,
               const float* __restrict__ fc2_w,
               const float* __restrict__ fc2_b,
               float* __restrict__ out)
{
  __shared__ __align__(16) ushort hA[MB * HST];   // h double-buffer (hi | lo)
  __shared__ __align__(16) ushort hB[MB * HST];
  __shared__ __align__(16) float  xs[MB * XSTR];
  __shared__ __align__(16) float  hf[MB * FSTR];  // final h fp32 (head; written once)
  __shared__ float zs[MB][16];

  const int tid  = threadIdx.x;
  const int b0   = blockIdx.x * MB;
  const int lane = tid & 63;
  const int wj   = tid >> 6;       // wave 0..7 -> tiles {2wj, 2wj+1}
  const int n    = lane & 15;      // MFMA col: batch n&7, type n>>3 (0=hi,1=lo)
  const int kg   = lane >> 4;      // k-group (A/B), row-quad (D)
  const int bat  = n & 7;
  const int nhi  = n >> 3;

  // ---- stage x (coalesced float4) ----
  for (int i = tid; i < MB * T / 4; i += TPB) {
    const int xb = i >> 7, tq = i & 127;
    float4 v = ((const float4*)(xg + (size_t)(b0 + xb) * T))[tq];
    *(float4*)&xs[xb * XSTR + tq * 4] = v;
  }
  // ---- zero h buffers (h0 = 0; pads stay 0) ----
  for (int i = tid; i < MB * HST; i += TPB) { hA[i] = 0; hB[i] = 0; }

  // ---- A-frags for tiles 2wj, 2wj+1 (gate-interleaved row permutation) ----
  short8 whi[2][2], wlo[2][2];     // [tile][k-half]
#pragma unroll
  for (int tt = 0; tt < 2; ++tt) {
    const int r    = 2 * wj + tt;
    const int arow = 64 * (n & 3) + 4 * r + (n >> 2);   // gate n&3, local unit n>>2
    const float* wr = W_hh + arow * H + 8 * kg;
    const float4 p0 = *(const float4*)(wr + 0);
    const float4 p1 = *(const float4*)(wr + 4);
    const float4 p2 = *(const float4*)(wr + 32);
    const float4 p3 = *(const float4*)(wr + 36);
    const float v0[8] = {p0.x, p0.y, p0.z, p0.w, p1.x, p1.y, p1.z, p1.w};
    const float v1[8] = {p2.x, p2.y, p2.z, p2.w, p3.x, p3.y, p3.z, p3.w};
#pragma unroll
    for (int j = 0; j < 8; ++j) {
      const ushort h0 = f2bf(v0[j]);
      whi[tt][0][j] = (short)h0;
      wlo[tt][0][j] = (short)f2bf(v0[j] - bf2f(h0));   // exact remainder, then RN
      const ushort h1 = f2bf(v1[j]);
      whi[tt][1][j] = (short)h1;
      wlo[tt][1][j] = (short)f2bf(v1[j] - bf2f(h1));
    }
  }

  // ---- owned c-state: unit u, batch bat ----
  const int u = 4 * (2 * wj + nhi) + kg;
  float bia[4], wih[4];
#pragma unroll
  for (int j = 0; j < 4; ++j) {                 // gate rows: i,f,g,o = 64j + u
    const int row = 64 * j + u;
    bia[j] = b_ih[row] + b_hh[row];
    wih[j] = W_ih[row];
  }

  const int rdoff = bat * HST + nhi * 64 + 8 * kg;  // B-frag read base (ushorts)
  const int woff  = bat * HST + u;                  // h write: hi at +0, lo at +64
  const float* xq = &xs[bat * XSTR];
  float c = 0.0f, hk = 0.0f;

  __syncthreads();

#define STEP(HR, HW, TT)                                                       \
  {                                                                            \
    const ushort* hb = (HR) + rdoff;                                           \
    const short8 f0 = *(const short8*)(hb + 0);    /* k 0..31  (hi or lo) */   \
    const short8 f1 = *(const short8*)(hb + 32);   /* k 32..63 */              \
    const floatx4 zf = {0.f, 0.f, 0.f, 0.f};                                   \
    floatx4 d1 = __builtin_amdgcn_mfma_f32_16x16x32_bf16(whi[0][0], f0, zf, 0, 0, 0); \
    floatx4 d2 = __builtin_amdgcn_mfma_f32_16x16x32_bf16(wlo[0][0], f0, zf, 0, 0, 0); \
    floatx4 e1 = __builtin_amdgcn_mfma_f32_16x16x32_bf16(whi[1][0], f0, zf, 0, 0, 0); \
    floatx4 e2 = __builtin_amdgcn_mfma_f32_16x16x32_bf16(wlo[1][0], f0, zf, 0, 0, 0); \
    d1 = __builtin_amdgcn_mfma_f32_16x16x32_bf16(whi[0][1], f1, d1, 0, 0, 0);  \
    d2 = __builtin_amdgcn_mfma_f32_16x16x32_bf16(wlo[0][1], f1, d2, 0, 0, 0);  \
    e1 = __builtin_amdgcn_mfma_f32_16x16x32_bf16(whi[1][1], f1, e1, 0, 0, 0);  \
    e2 = __builtin_amdgcn_mfma_f32_16x16x32_bf16(wlo[1][1], f1, e2, 0, 0, 0);  \
    const float xt = xq[(TT)];                                                 \
    float p[4];                                                                \
    _Pragma("unroll") for (int j = 0; j < 4; ++j) {                            \
      const float sA = d1[j] + d2[j];            /* tile 2wj   partial */      \
      const float sB = e1[j] + e2[j];            /* tile 2wj+1 partial */      \
      const float pA = sA + swz8(sA);            /* + partner col (hi/lo) */   \
      const float pB = sB + swz8(sB);                                          \
      p[j] = (nhi ? pB : pA) + fmaf(xt, wih[j], bia[j]);                       \
    }                                                                          \
    const float ig = fsig(p[0]);                                               \
    const float fg = fsig(p[1]);                                               \
    const float gc = ftanh(p[2]);                                              \
    const float og = fsig(p[3]);                                               \
    c  = fmaf(fg, c, ig * gc);                                                 \
    hk = og * ftanh(c);                                                        \
    const ushort hib = f2bf(hk);                                               \
    ushort* hw = (HW) + woff;                                                  \
    hw[0]  = hib;                                                              \
    hw[64] = f2bf(hk - bf2f(hib));                                             \
    __syncthreads();                                                           \
  }

  for (int t = 0; t < T; t += 2) {
    STEP(hA, hB, t);
    STEP(hB, hA, t + 1);
  }
#undef STEP

  // ---- final h (fp32, from registers) -> LDS once; then the head ----
  hf[bat * FSTR + u] = hk;
  __syncthreads();
  if (tid < MB * 16) {
    const int bq = tid >> 4, j2 = tid & 15;   // 8 batches x 16 hidden2
    float s = fc1_b[j2];
    const float* fw = fc1_w + j2 * H;
#pragma unroll
    for (int k = 0; k < H; ++k) s = fmaf(hf[bq * FSTR + k], fw[k], s);
    s = fmaxf(s, 0.0f);
    zs[bq][j2] = s * fc2_w[j2];
  }
  __syncthreads();
  if (tid < MB) {
    float s = fc2_b[0];
#pragma unroll
    for (int j = 0; j < 16; ++j) s += zs[tid][j];
    out[b0 + tid] = s;
  }
}

}  // namespace

extern "C" void kernel_launch(void* const* d_in, const int* in_sizes, int n_in,
                              void* d_out, int out_size, void* d_ws, size_t ws_size,
                              hipStream_t stream) {
  const float* xg    = (const float*)d_in[0];
  const float* W_ih  = (const float*)d_in[1];
  const float* W_hh  = (const float*)d_in[2];
  const float* b_ih  = (const float*)d_in[3];
  const float* b_hh  = (const float*)d_in[4];
  const float* fc1_w = (const float*)d_in[5];
  const float* fc1_b = (const float*)d_in[6];
  const float* fc2_w = (const float*)d_in[7];
  const float* fc2_b = (const float*)d_in[8];
  float* out = (float*)d_out;

  dim3 grid(2048 / MB);   // 256 blocks -> 1 per CU, 8 waves = 2/SIMD
  dim3 block(TPB);
  hipLaunchKernelGGL(lstm_mfma, grid, block, 0, stream,
                     xg, W_ih, W_hh, b_ih, b_hh, fc1_w, fc1_b, fc2_w, fc2_b, out);
}